// Round 1
// baseline (406.639 us; speedup 1.0000x reference)
//
#include <hip/hip_runtime.h>
#include <math.h>

// Problem constants
#define TT       16      // sequence length T
#define NSEQ     256     // B*H*W sequences
#define TOK      4096    // NSEQ * TT tokens
#define DMODEL   512
#define DINNER   1024
#define DSTATE   64
#define NHEADS   16
#define HEADDIM  64
#define CONVDIM  1152    // D_INNER + 2*D_STATE
#define DINPROJ  2192    // 2*D_INNER + 2*D_STATE + NHEADS

// token permutation: v = t*256 + (h*16+w)  <->  u = (h*16+w)*16 + t
__device__ __forceinline__ int perm_vu(int v) { return (v & 255) * 16 + (v >> 8); }

// Generic tiled fp32 GEMM: C[m][n] = sum_k A(m,k) * B[n*ldb + k] (+ bias[n])
//   A_KMAJOR:  A(m,k) = A[k*lda + m]           (else A[rowA(m)*lda + k])
//   PERM_A:    rowA(m) = perm_vu(m)            (only when !A_KMAJOR)
//   PERM_C:    output row = perm_vu(m)
//   C_COLMAJOR: store C[n*ldc + row]           (else C[row*ldc + n])
// Tiles: BM=128, BN=64, BK=16; 256 threads; 8x4 micro-tile per thread.
// M must be a multiple of 128; K a multiple of 16; N is guarded.
template<bool A_KMAJOR, bool PERM_A, bool PERM_C, bool C_COLMAJOR>
__global__ __launch_bounds__(256) void gemm_kernel(
    const float* __restrict__ A, const float* __restrict__ B,
    const float* __restrict__ bias, float* __restrict__ C,
    int N, int K, int lda, int ldb, int ldc)
{
    __shared__ float As[16][132];   // [k][m], padded (bank = (4k+m)%32)
    __shared__ float Bs[16][68];    // [k][n], padded

    const int tid = threadIdx.x;
    const int m0 = blockIdx.x * 128;
    const int n0 = blockIdx.y * 64;
    const int tx = tid & 15;        // -> 4 cols
    const int ty = tid >> 4;        // -> 8 rows

    float acc[8][4];
#pragma unroll
    for (int i = 0; i < 8; i++)
#pragma unroll
        for (int j = 0; j < 4; j++) acc[i][j] = 0.f;

    for (int k0 = 0; k0 < K; k0 += 16) {
        // ---- stage A tile (128 m x 16 k) ----
        if (A_KMAJOR) {
            const int r  = tid >> 4;         // k 0..15
            const int c8 = (tid & 15) * 8;   // m
            const float* src = A + (size_t)(k0 + r) * lda + m0 + c8;
            float4 v0 = *(const float4*)(src);
            float4 v1 = *(const float4*)(src + 4);
            *(float4*)&As[r][c8]     = v0;
            *(float4*)&As[r][c8 + 4] = v1;
        } else {
            const int r  = tid >> 1;         // m 0..127
            const int k8 = (tid & 1) * 8;    // k
            const int rowm = PERM_A ? perm_vu(m0 + r) : (m0 + r);
            const float* src = A + (size_t)rowm * lda + k0 + k8;
            float4 v0 = *(const float4*)(src);
            float4 v1 = *(const float4*)(src + 4);
            As[k8 + 0][r] = v0.x; As[k8 + 1][r] = v0.y;
            As[k8 + 2][r] = v0.z; As[k8 + 3][r] = v0.w;
            As[k8 + 4][r] = v1.x; As[k8 + 5][r] = v1.y;
            As[k8 + 6][r] = v1.z; As[k8 + 7][r] = v1.w;
        }
        // ---- stage B tile (64 n x 16 k) ----
        {
            const int r  = tid >> 2;         // n 0..63
            const int k4 = (tid & 3) * 4;    // k
            float4 v = make_float4(0.f, 0.f, 0.f, 0.f);
            if (n0 + r < N) v = *(const float4*)(B + (size_t)(n0 + r) * ldb + k0 + k4);
            Bs[k4 + 0][r] = v.x; Bs[k4 + 1][r] = v.y;
            Bs[k4 + 2][r] = v.z; Bs[k4 + 3][r] = v.w;
        }
        __syncthreads();

#pragma unroll
        for (int k = 0; k < 16; k++) {
            float4 a0 = *(const float4*)&As[k][ty * 8];
            float4 a1 = *(const float4*)&As[k][ty * 8 + 4];
            float4 b0 = *(const float4*)&Bs[k][tx * 4];
            const float av[8] = {a0.x, a0.y, a0.z, a0.w, a1.x, a1.y, a1.z, a1.w};
            const float bv[4] = {b0.x, b0.y, b0.z, b0.w};
#pragma unroll
            for (int i = 0; i < 8; i++)
#pragma unroll
                for (int j = 0; j < 4; j++)
                    acc[i][j] = fmaf(av[i], bv[j], acc[i][j]);
        }
        __syncthreads();
    }

    // ---- epilogue ----
    float bv[4];
#pragma unroll
    for (int j = 0; j < 4; j++) {
        int n = n0 + tx * 4 + j;
        bv[j] = (bias != nullptr && n < N) ? bias[n] : 0.f;
    }
#pragma unroll
    for (int i = 0; i < 8; i++) {
        int m = m0 + ty * 8 + i;
        int row = PERM_C ? perm_vu(m) : m;
#pragma unroll
        for (int j = 0; j < 4; j++) {
            int n = n0 + tx * 4 + j;
            if (n < N) {
                float v = acc[i][j] + bv[j];
                if (C_COLMAJOR) C[(size_t)n * ldc + row] = v;
                else            C[(size_t)row * ldc + n] = v;
            }
        }
    }
}

// Depthwise causal conv over T (D_CONV=4) + bias + SiLU.
// zxbcdt rows are u = n*16 + t (sequence-major); xBC part starts at col DINNER.
__global__ __launch_bounds__(128) void conv_silu_kernel(
    const float* __restrict__ zxbcdt, const float* __restrict__ conv_w,
    const float* __restrict__ conv_b, float* __restrict__ xBCc)
{
    const int ch = blockIdx.x * 128 + threadIdx.x;   // 0..1151
    const int u  = blockIdx.y;                        // 0..4095
    const int n = u >> 4, t = u & 15;
    float acc = conv_b[ch];
#pragma unroll
    for (int k = 0; k < 4; k++) {
        int tt = t - 3 + k;
        if (tt >= 0)
            acc = fmaf(zxbcdt[(size_t)(n * 16 + tt) * DINPROJ + DINNER + ch],
                       conv_w[ch * 4 + k], acc);
    }
    float s = acc / (1.f + expf(-acc));  // silu
    xBCc[(size_t)u * CONVDIM + ch] = s;
}

// Selective scan + D-skip + z-gating + RMSNorm, fused.
// One block per sequence n: 1024 threads = 16 waves; wave = head, lane = p.
// State h[p][s] lives in 64 VGPRs per lane.
__global__ __launch_bounds__(1024) void scan_kernel(
    const float* __restrict__ zxbcdt, const float* __restrict__ xBCc,
    const float* __restrict__ dt_bias, const float* __restrict__ A_log,
    const float* __restrict__ Dp, const float* __restrict__ norm_w,
    float* __restrict__ yn)
{
    const int n = blockIdx.x;
    const int tid = threadIdx.x;
    const int head = tid >> 6;
    const int p = tid & 63;

    __shared__ float Bsh[64];
    __shared__ float Csh[64];
    __shared__ float red[16];

    float h[64];
#pragma unroll
    for (int s = 0; s < 64; s++) h[s] = 0.f;

    const float Ah  = -expf(A_log[head]);
    const float dtb = dt_bias[head];
    const float Dh  = Dp[head];
    const float nw  = norm_w[head * 64 + p];

    for (int t = 0; t < TT; t++) {
        const int u = n * 16 + t;
        __syncthreads();  // protect Bsh/Csh/red from previous iteration's reads
        if (tid < 64)       Bsh[tid]      = xBCc[(size_t)u * CONVDIM + DINNER + tid];
        else if (tid < 128) Csh[tid - 64] = xBCc[(size_t)u * CONVDIM + DINNER + 64 + (tid - 64)];
        __syncthreads();

        const float x_p = xBCc[(size_t)u * CONVDIM + head * 64 + p];
        float dtraw = zxbcdt[(size_t)u * DINPROJ + (DINNER + CONVDIM) + head] + dtb;
        float dtv = (dtraw > 20.f) ? dtraw : log1pf(expf(dtraw));  // softplus
        const float dA = expf(dtv * Ah);
        const float dx = dtv * x_p;

        float y = 0.f;
#pragma unroll
        for (int s = 0; s < 64; s++) {
            h[s] = fmaf(h[s], dA, dx * Bsh[s]);
            y = fmaf(h[s], Csh[s], y);
        }
        float yv = fmaf(Dh, x_p, y);

        const float z = zxbcdt[(size_t)u * DINPROJ + head * 64 + p];
        const float g = yv * (z / (1.f + expf(-z)));  // * silu(z)

        // RMS norm over the block's 1024 channels
        float ss = g * g;
#pragma unroll
        for (int off = 32; off >= 1; off >>= 1) ss += __shfl_xor(ss, off);
        if (p == 0) red[head] = ss;
        __syncthreads();
        float tot = 0.f;
#pragma unroll
        for (int i = 0; i < 16; i++) tot += red[i];
        const float scale = rsqrtf(tot * (1.f / 1024.f) + 1e-5f);

        yn[(size_t)u * DINNER + head * 64 + p] = g * scale * nw;
    }
}

extern "C" void kernel_launch(void* const* d_in, const int* in_sizes, int n_in,
                              void* d_out, int out_size, void* d_ws, size_t ws_size,
                              hipStream_t stream) {
    const float* hs         = (const float*)d_in[0];   // (1,512,16,16,16)
    const float* proj_in_w  = (const float*)d_in[1];   // (512,512)
    const float* proj_in_b  = (const float*)d_in[2];   // (512)
    const float* proj_out_w = (const float*)d_in[3];   // (512,512)
    const float* proj_out_b = (const float*)d_in[4];   // (512)
    const float* in_proj_w  = (const float*)d_in[5];   // (2192,512)
    const float* conv_w     = (const float*)d_in[6];   // (1152,4)
    const float* conv_b     = (const float*)d_in[7];   // (1152)
    const float* dt_bias    = (const float*)d_in[8];   // (16)
    const float* A_log      = (const float*)d_in[9];   // (16)
    const float* Dp         = (const float*)d_in[10];  // (16)
    const float* norm_w     = (const float*)d_in[11];  // (1024)
    const float* out_proj_w = (const float*)d_in[12];  // (512,1024)
    float* out = (float*)d_out;

    float* ws = (float*)d_ws;
    float* xv     = ws;                                // 4096*512   (v-order tokens)
    float* zxbcdt = xv + (size_t)TOK * DMODEL;         // 4096*2192  (u-order)
    float* xBCc   = zxbcdt + (size_t)TOK * DINPROJ;    // 4096*1152  (u-order)
    float* yn     = xBCc + (size_t)TOK * CONVDIM;      // 4096*1024  (u-order)
    float* y2     = xv;                                // reuse xv (dead after K2)

    dim3 blk(256);

    // K1: xv[v][d] = sum_c hs[c][v] * proj_in_w[d][c] + proj_in_b[d]
    gemm_kernel<true, false, false, false><<<dim3(32, 8), blk, 0, stream>>>(
        hs, proj_in_w, proj_in_b, xv, DMODEL, 512, TOK, 512, DMODEL);

    // K2: zxbcdt[u(v)][e] = sum_d xv[v][d] * in_proj_w[e][d]
    gemm_kernel<false, false, true, false><<<dim3(32, 35), blk, 0, stream>>>(
        xv, in_proj_w, nullptr, zxbcdt, DINPROJ, DMODEL, DMODEL, DMODEL, DINPROJ);

    // K3: causal conv + SiLU -> xBCc[u][1152]
    conv_silu_kernel<<<dim3(9, TOK), dim3(128), 0, stream>>>(zxbcdt, conv_w, conv_b, xBCc);

    // K4: scan + gate + RMSNorm -> yn[u][1024]
    scan_kernel<<<dim3(NSEQ), dim3(1024), 0, stream>>>(
        zxbcdt, xBCc, dt_bias, A_log, Dp, norm_w, yn);

    // K6: y2[u][o] = sum_d yn[u][d] * out_proj_w[o][d]
    gemm_kernel<false, false, false, false><<<dim3(32, 8), blk, 0, stream>>>(
        yn, out_proj_w, nullptr, y2, DMODEL, DINNER, DINNER, DINNER, DMODEL);

    // K7: out[c][v] = sum_d y2[u(v)][d] * proj_out_w[c][d] + proj_out_b[c]
    gemm_kernel<false, true, false, true><<<dim3(32, 8), blk, 0, stream>>>(
        y2, proj_out_w, proj_out_b, out, DMODEL, DMODEL, DMODEL, DMODEL, TOK);
}

// Round 2
// 173.081 us; speedup vs baseline: 2.3494x; 2.3494x over previous
//
#include <hip/hip_runtime.h>
#include <hip/hip_bf16.h>
#include <math.h>

// Problem constants
#define TT       16      // sequence length T
#define NSEQ     256     // B*H*W sequences
#define TOK      4096    // NSEQ * TT tokens
#define DMODEL   512
#define DINNER   1024
#define DSTATE   64
#define NHEADS   16
#define HEADDIM  64
#define CONVDIM  1152    // D_INNER + 2*D_STATE
#define DINPROJ  2192    // 2*D_INNER + 2*D_STATE + NHEADS
#define DTOFF    2176    // D_INNER + CONV_DIM (start of dt columns)
#define NPAD_IP  2304    // in_proj rows padded to multiple of 128

using bf16x8 = __attribute__((ext_vector_type(8))) short;
using f32x4  = __attribute__((ext_vector_type(4))) float;
typedef __hip_bfloat16 bf16;

__device__ __forceinline__ void gload_lds16(const void* g, void* l) {
    __builtin_amdgcn_global_load_lds(
        (const __attribute__((address_space(1))) unsigned int*)g,
        (__attribute__((address_space(3))) unsigned int*)l,
        16, 0, 0);
}

// ---------------------------------------------------------------------------
// MFMA bf16 GEMM: C[M][N] = A[M][K] * B[N][K]^T (+ bias)
// 128x128 tile, BK=32, 256 threads (4 waves, 2x2 wave grid), m97 structure.
// M % 128 == 0, K % 32 == 0, B has >= ceil128(N) valid rows (zero-padded),
// stores guarded by col < Nreal.
// BIAS: 0 none, 1 per-col (bias[n]), 2 per-row (bias[m]).
// OUTBF: store bf16 to Ch, else fp32 to Cf.  DUAL: also store fp32 to C2.
// ---------------------------------------------------------------------------
template<bool OUTBF, bool DUAL, int BIAS>
__global__ __launch_bounds__(256) void mfma_gemm(
    const bf16* __restrict__ A, const bf16* __restrict__ B,
    const float* __restrict__ bias, float* __restrict__ Cf,
    bf16* __restrict__ Ch, float* __restrict__ C2,
    int Nreal, int K, int lda, int ldb, int ldc)
{
    __shared__ short As[128 * 32];
    __shared__ short Bs[128 * 32];

    const int tid = threadIdx.x;
    const int wv = tid >> 6, ln = tid & 63;
    const int m0 = blockIdx.x * 128, n0 = blockIdx.y * 128;
    const int wr = wv >> 1, wc = wv & 1;        // 2x2 wave grid, 64x64 each
    const int lr = ln & 15, lk = (ln >> 4) * 8; // fragment row / k-offset

    f32x4 acc[4][4];
#pragma unroll
    for (int m = 0; m < 4; ++m)
#pragma unroll
        for (int n = 0; n < 4; ++n) acc[m][n] = (f32x4){0.f, 0.f, 0.f, 0.f};

    for (int k0 = 0; k0 < K; k0 += 32) {
        __syncthreads();   // previous iteration's reads done
#pragma unroll
        for (int r = 0; r < 2; ++r) {
            const int ofs = r * 4096 + wv * 1024 + ln * 16;  // byte in 8KB tile
            const int row = ofs >> 6;                         // 64 B per row
            const int ke  = (ofs & 63) >> 1;                  // element in row
            gload_lds16(A + (size_t)(m0 + row) * lda + k0 + ke, (char*)As + ofs);
            gload_lds16(B + (size_t)(n0 + row) * ldb + k0 + ke, (char*)Bs + ofs);
        }
        __syncthreads();   // staging complete (vmcnt drained by barrier)

        bf16x8 af[4], bfr[4];
#pragma unroll
        for (int m = 0; m < 4; ++m)
            af[m] = *(const bf16x8*)&As[(wr * 64 + m * 16 + lr) * 32 + lk];
#pragma unroll
        for (int n = 0; n < 4; ++n)
            bfr[n] = *(const bf16x8*)&Bs[(wc * 64 + n * 16 + lr) * 32 + lk];
#pragma unroll
        for (int m = 0; m < 4; ++m)
#pragma unroll
            for (int n = 0; n < 4; ++n)
                acc[m][n] = __builtin_amdgcn_mfma_f32_16x16x32_bf16(
                    af[m], bfr[n], acc[m][n], 0, 0, 0);
    }

    // epilogue: C/D mapping col = lane&15, row = (lane>>4)*4 + reg
    const int mBase = m0 + wr * 64, nBase = n0 + wc * 64;
#pragma unroll
    for (int m = 0; m < 4; ++m) {
#pragma unroll
        for (int n = 0; n < 4; ++n) {
            const int col = nBase + n * 16 + lr;
            if (col < Nreal) {
#pragma unroll
                for (int j = 0; j < 4; ++j) {
                    const int row = mBase + m * 16 + (ln >> 4) * 4 + j;
                    float v = acc[m][n][j];
                    if (BIAS == 1) v += bias[col];
                    if (BIAS == 2) v += bias[row];
                    if (OUTBF) {
                        Ch[(size_t)row * ldc + col] = __float2bfloat16(v);
                        if (DUAL) C2[(size_t)row * ldc + col] = v;
                    } else {
                        Cf[(size_t)row * ldc + col] = v;
                    }
                }
            }
        }
    }
}

// ---------------------------------------------------------------------------
// Weight fp32 -> bf16 conversion (+ zero pad for in_proj rows 2192..2303)
// ---------------------------------------------------------------------------
#define SZ_PI  (512 * 512)
#define SZ_PO  (512 * 512)
#define SZ_OP  (512 * 1024)
#define SZ_IP  (DINPROJ * 512)
#define SZ_IPP (NPAD_IP * 512)
#define SZ_ALL (SZ_PI + SZ_PO + SZ_OP + SZ_IPP)

__global__ __launch_bounds__(256) void prep_weights(
    const float* __restrict__ pi, const float* __restrict__ po,
    const float* __restrict__ op, const float* __restrict__ ip,
    bf16* __restrict__ wpi, bf16* __restrict__ wpo,
    bf16* __restrict__ wop, bf16* __restrict__ wip)
{
    for (int idx = blockIdx.x * 256 + threadIdx.x; idx < SZ_ALL;
         idx += gridDim.x * 256) {
        if (idx < SZ_PI) {
            wpi[idx] = __float2bfloat16(pi[idx]);
        } else if (idx < SZ_PI + SZ_PO) {
            int j = idx - SZ_PI; wpo[j] = __float2bfloat16(po[j]);
        } else if (idx < SZ_PI + SZ_PO + SZ_OP) {
            int j = idx - SZ_PI - SZ_PO; wop[j] = __float2bfloat16(op[j]);
        } else {
            int j = idx - SZ_PI - SZ_PO - SZ_OP;
            wip[j] = (j < SZ_IP) ? __float2bfloat16(ip[j]) : __float2bfloat16(0.f);
        }
    }
}

// ---------------------------------------------------------------------------
// hs fp32 [512 c][4096 v] -> hsT bf16 [4096 v][512 c]
// ---------------------------------------------------------------------------
__global__ __launch_bounds__(256) void transpose_hs(
    const float* __restrict__ hs, bf16* __restrict__ hsT)
{
    __shared__ float tile[32][33];
    const int v0 = blockIdx.x * 32, c0 = blockIdx.y * 32;
    const int tx = threadIdx.x, ty = threadIdx.y;   // 32 x 8
#pragma unroll
    for (int i = 0; i < 4; ++i)
        tile[ty + 8 * i][tx] = hs[(size_t)(c0 + ty + 8 * i) * TOK + v0 + tx];
    __syncthreads();
#pragma unroll
    for (int i = 0; i < 4; ++i)
        hsT[(size_t)(v0 + ty + 8 * i) * DMODEL + c0 + tx] =
            __float2bfloat16(tile[tx][ty + 8 * i]);
}

// ---------------------------------------------------------------------------
// Recompute the 16 dt columns of zxbcdt in fp32 (exp-sensitive path).
// One block per token v; 4 waves x 4 heads each; lane covers 8 of 512 k.
// ---------------------------------------------------------------------------
__global__ __launch_bounds__(256) void dt_fix_kernel(
    const float* __restrict__ xv32, const float* __restrict__ in_proj_w,
    float* __restrict__ zxbcdt)
{
    const int v = blockIdx.x;
    const int w = threadIdx.x >> 6, l = threadIdx.x & 63;
    const float4* xr = (const float4*)(xv32 + (size_t)v * DMODEL);
    const float4 x0 = xr[l * 2], x1 = xr[l * 2 + 1];
#pragma unroll
    for (int hh = 0; hh < 4; ++hh) {
        const int h = w * 4 + hh;
        const float4* wr = (const float4*)(in_proj_w + (size_t)(DTOFF + h) * DMODEL);
        const float4 w0 = wr[l * 2], w1 = wr[l * 2 + 1];
        float dot = x0.x * w0.x + x0.y * w0.y + x0.z * w0.z + x0.w * w0.w
                  + x1.x * w1.x + x1.y * w1.y + x1.z * w1.z + x1.w * w1.w;
#pragma unroll
        for (int off = 32; off >= 1; off >>= 1) dot += __shfl_xor(dot, off);
        if (l == 0) zxbcdt[(size_t)v * DINPROJ + DTOFF + h] = dot;
    }
}

// ---------------------------------------------------------------------------
// Depthwise causal conv over T (D_CONV=4) + bias + SiLU.
// zxbcdt rows are v = t*256 + n; output xBCc rows are u = n*16 + t.
// ---------------------------------------------------------------------------
__global__ __launch_bounds__(128) void conv_silu_kernel(
    const float* __restrict__ zxbcdt, const float* __restrict__ conv_w,
    const float* __restrict__ conv_b, float* __restrict__ xBCc)
{
    const int ch = blockIdx.x * 128 + threadIdx.x;   // 0..1151
    const int u  = blockIdx.y;                        // 0..4095
    const int n = u >> 4, t = u & 15;
    float acc = conv_b[ch];
#pragma unroll
    for (int k = 0; k < 4; ++k) {
        const int tt = t - 3 + k;
        if (tt >= 0)
            acc = fmaf(zxbcdt[(size_t)(tt * 256 + n) * DINPROJ + DINNER + ch],
                       conv_w[ch * 4 + k], acc);
    }
    xBCc[(size_t)u * CONVDIM + ch] = acc / (1.f + expf(-acc));
}

// ---------------------------------------------------------------------------
// Selective scan + D-skip + z-gating + RMSNorm, fused.
// One block per sequence n: 1024 threads = 16 waves; wave = head, lane = p.
// Reads z/dt from zxbcdt (v-order), x/B/C from xBCc (u-order);
// writes yn bf16 in v-order.
// ---------------------------------------------------------------------------
__global__ __launch_bounds__(1024) void scan_kernel(
    const float* __restrict__ zxbcdt, const float* __restrict__ xBCc,
    const float* __restrict__ dt_bias, const float* __restrict__ A_log,
    const float* __restrict__ Dp, const float* __restrict__ norm_w,
    bf16* __restrict__ yn)
{
    const int n = blockIdx.x;
    const int tid = threadIdx.x;
    const int head = tid >> 6;
    const int p = tid & 63;

    __shared__ float Bsh[64];
    __shared__ float Csh[64];
    __shared__ float red[16];

    float h[64];
#pragma unroll
    for (int s = 0; s < 64; ++s) h[s] = 0.f;

    const float Ah  = -expf(A_log[head]);
    const float dtb = dt_bias[head];
    const float Dh  = Dp[head];
    const float nw  = norm_w[head * 64 + p];

    for (int t = 0; t < TT; ++t) {
        const int u = n * 16 + t;
        const int v = t * 256 + n;
        __syncthreads();  // protect Bsh/Csh/red from previous iteration's reads
        if (tid < 64)       Bsh[tid]      = xBCc[(size_t)u * CONVDIM + DINNER + tid];
        else if (tid < 128) Csh[tid - 64] = xBCc[(size_t)u * CONVDIM + DINNER + 64 + (tid - 64)];
        __syncthreads();

        const float x_p = xBCc[(size_t)u * CONVDIM + head * 64 + p];
        float dtraw = zxbcdt[(size_t)v * DINPROJ + DTOFF + head] + dtb;
        float dtv = (dtraw > 20.f) ? dtraw : log1pf(expf(dtraw));  // softplus
        const float dA = expf(dtv * Ah);
        const float dx = dtv * x_p;

        float y = 0.f;
#pragma unroll
        for (int s = 0; s < 64; ++s) {
            h[s] = fmaf(h[s], dA, dx * Bsh[s]);
            y = fmaf(h[s], Csh[s], y);
        }
        const float yv = fmaf(Dh, x_p, y);

        const float z = zxbcdt[(size_t)v * DINPROJ + head * 64 + p];
        const float g = yv * (z / (1.f + expf(-z)));  // * silu(z)

        // RMS norm over the block's 1024 channels
        float ss = g * g;
#pragma unroll
        for (int off = 32; off >= 1; off >>= 1) ss += __shfl_xor(ss, off);
        if (p == 0) red[head] = ss;
        __syncthreads();
        float tot = 0.f;
#pragma unroll
        for (int i = 0; i < 16; ++i) tot += red[i];
        const float scale = rsqrtf(tot * (1.f / 1024.f) + 1e-5f);

        yn[(size_t)v * DINNER + head * 64 + p] = __float2bfloat16(g * scale * nw);
    }
}

// ---------------------------------------------------------------------------
extern "C" void kernel_launch(void* const* d_in, const int* in_sizes, int n_in,
                              void* d_out, int out_size, void* d_ws, size_t ws_size,
                              hipStream_t stream) {
    const float* hs         = (const float*)d_in[0];   // (1,512,16,16,16)
    const float* proj_in_w  = (const float*)d_in[1];   // (512,512)
    const float* proj_in_b  = (const float*)d_in[2];   // (512)
    const float* proj_out_w = (const float*)d_in[3];   // (512,512)
    const float* proj_out_b = (const float*)d_in[4];   // (512)
    const float* in_proj_w  = (const float*)d_in[5];   // (2192,512)
    const float* conv_w     = (const float*)d_in[6];   // (1152,4)
    const float* conv_b     = (const float*)d_in[7];   // (1152)
    const float* dt_bias    = (const float*)d_in[8];   // (16)
    const float* A_log      = (const float*)d_in[9];   // (16)
    const float* Dp         = (const float*)d_in[10];  // (16)
    const float* norm_w     = (const float*)d_in[11];  // (1024)
    const float* out_proj_w = (const float*)d_in[12];  // (512,1024)
    float* out = (float*)d_out;

    // workspace layout (fp32 first, then bf16)
    float* ws      = (float*)d_ws;
    float* zxbcdt  = ws;                                   // 4096*2192 f32
    float* xBCc    = zxbcdt + (size_t)TOK * DINPROJ;       // 4096*1152 f32
    float* xv32    = xBCc + (size_t)TOK * CONVDIM;         // 4096*512  f32
    bf16*  bfb     = (bf16*)(xv32 + (size_t)TOK * DMODEL);
    bf16*  hsT     = bfb;                                  // 4096*512
    bf16*  xv_bf   = hsT + (size_t)TOK * DMODEL;           // 4096*512
    bf16*  yn      = xv_bf + (size_t)TOK * DMODEL;         // 4096*1024
    bf16*  y2      = yn + (size_t)TOK * DINNER;            // 4096*512
    bf16*  wpi     = y2 + (size_t)TOK * DMODEL;            // 512*512
    bf16*  wpo     = wpi + SZ_PI;                          // 512*512
    bf16*  wop     = wpo + SZ_PO;                          // 512*1024
    bf16*  wip     = wop + SZ_OP;                          // 2304*512

    // P0: weights -> bf16 (+pad), hs -> transposed bf16
    prep_weights<<<1024, 256, 0, stream>>>(proj_in_w, proj_out_w, out_proj_w,
                                           in_proj_w, wpi, wpo, wop, wip);
    transpose_hs<<<dim3(128, 16), dim3(32, 8), 0, stream>>>(hs, hsT);

    // K1: xv[v][d] = hsT[v][:] . wpi[d][:] + b[d]   (bf16 out + fp32 dual)
    mfma_gemm<true, true, 1><<<dim3(32, 4), 256, 0, stream>>>(
        hsT, wpi, proj_in_b, nullptr, xv_bf, xv32, DMODEL, DMODEL, DMODEL, DMODEL, DMODEL);

    // K2: zxbcdt[v][e] = xv[v][:] . wip[e][:]   (fp32 out, N guarded at 2192)
    mfma_gemm<false, false, 0><<<dim3(32, 18), 256, 0, stream>>>(
        xv_bf, wip, nullptr, zxbcdt, nullptr, nullptr, DINPROJ, DMODEL, DMODEL, DMODEL, DINPROJ);

    // K2b: recompute dt columns in fp32
    dt_fix_kernel<<<TOK, 256, 0, stream>>>(xv32, in_proj_w, zxbcdt);

    // K3: causal conv + SiLU -> xBCc[u][1152]
    conv_silu_kernel<<<dim3(9, TOK), dim3(128), 0, stream>>>(zxbcdt, conv_w, conv_b, xBCc);

    // K4: scan + gate + RMSNorm -> yn (bf16, v-order)
    scan_kernel<<<dim3(NSEQ), dim3(1024), 0, stream>>>(
        zxbcdt, xBCc, dt_bias, A_log, Dp, norm_w, yn);

    // K6: y2[v][o] = yn[v][:] . wop[o][:]   (bf16 out)
    mfma_gemm<true, false, 0><<<dim3(32, 4), 256, 0, stream>>>(
        yn, wop, nullptr, nullptr, y2, nullptr, DMODEL, DINNER, DINNER, DINNER, DMODEL);

    // K7: out[c][v] = wpo[c][:] . y2[v][:] + pob[c]   (fp32, row-major = out layout)
    mfma_gemm<false, false, 2><<<dim3(4, 32), 256, 0, stream>>>(
        wpo, y2, proj_out_b, out, nullptr, nullptr, TOK, DMODEL, DMODEL, DMODEL, TOK);
}

// Round 3
// 132.280 us; speedup vs baseline: 3.0741x; 1.3084x over previous
//
#include <hip/hip_runtime.h>
#include <hip/hip_bf16.h>
#include <math.h>

// Problem constants
#define TT       16      // sequence length T
#define NSEQ     256     // B*H*W sequences
#define TOK      4096    // NSEQ * TT tokens
#define DMODEL   512
#define DINNER   1024
#define DSTATE   64
#define NHEADS   16
#define HEADDIM  64
#define CONVDIM  1152    // D_INNER + 2*D_STATE
#define DINPROJ  2192    // 2*D_INNER + 2*D_STATE + NHEADS
#define DTOFF    2176    // D_INNER + CONV_DIM (start of dt columns)
#define NPAD_IP  2304    // in_proj rows padded to multiple of 128

using bf16x8 = __attribute__((ext_vector_type(8))) short;
using f32x4  = __attribute__((ext_vector_type(4))) float;
typedef __hip_bfloat16 bf16;

__device__ __forceinline__ void gload_lds16(const void* g, void* l) {
    __builtin_amdgcn_global_load_lds(
        (const __attribute__((address_space(1))) unsigned int*)g,
        (__attribute__((address_space(3))) unsigned int*)l,
        16, 0, 0);
}

// ---------------------------------------------------------------------------
// MFMA bf16 GEMM: C[M][N] = A[M][K] * B[N][K]^T (+ bias)
// 128 x (NFRAG*32) tile, BK=32, 256 threads (4 waves, 2x2 wave grid).
// M % 128 == 0, K % 32 == 0, B has >= gridDim.y*BN valid rows (zero-padded),
// stores guarded by col < Nreal.
// BIAS: 0 none, 1 per-col (bias[n]), 2 per-row (bias[m]).
// OUTBF: store bf16 to Ch, else fp32 to Cf.  DUAL: also store fp32 to C2.
// ---------------------------------------------------------------------------
template<int NFRAG, bool OUTBF, bool DUAL, int BIAS>
__global__ __launch_bounds__(256) void mfma_gemm(
    const bf16* __restrict__ A, const bf16* __restrict__ B,
    const float* __restrict__ bias, float* __restrict__ Cf,
    bf16* __restrict__ Ch, float* __restrict__ C2,
    int Nreal, int K, int lda, int ldb, int ldc)
{
    constexpr int BN = NFRAG * 32;
    __shared__ short As[128 * 32];
    __shared__ short Bs[BN * 32];

    const int tid = threadIdx.x;
    const int wv = tid >> 6, ln = tid & 63;
    const int m0 = blockIdx.x * 128, n0 = blockIdx.y * BN;
    const int wr = wv >> 1, wc = wv & 1;        // 2x2 wave grid
    const int lr = ln & 15, lk = (ln >> 4) * 8; // fragment row / k-offset

    f32x4 acc[4][NFRAG];
#pragma unroll
    for (int m = 0; m < 4; ++m)
#pragma unroll
        for (int n = 0; n < NFRAG; ++n) acc[m][n] = (f32x4){0.f, 0.f, 0.f, 0.f};

    for (int k0 = 0; k0 < K; k0 += 32) {
        __syncthreads();   // previous iteration's reads done
#pragma unroll
        for (int r = 0; r < 2; ++r) {
            const int ofs = r * 4096 + tid * 16;    // byte in 8KB A tile
            const int row = ofs >> 6;               // 64 B per row
            const int ke  = (ofs & 63) >> 1;        // element in row
            gload_lds16(A + (size_t)(m0 + row) * lda + k0 + ke, (char*)As + ofs);
        }
#pragma unroll
        for (int r = 0; r < NFRAG / 2; ++r) {
            const int ofs = r * 4096 + tid * 16;
            const int row = ofs >> 6;
            const int ke  = (ofs & 63) >> 1;
            gload_lds16(B + (size_t)(n0 + row) * ldb + k0 + ke, (char*)Bs + ofs);
        }
        __syncthreads();   // staging complete

        bf16x8 af[4], bfr[NFRAG];
#pragma unroll
        for (int m = 0; m < 4; ++m)
            af[m] = *(const bf16x8*)&As[(wr * 64 + m * 16 + lr) * 32 + lk];
#pragma unroll
        for (int n = 0; n < NFRAG; ++n)
            bfr[n] = *(const bf16x8*)&Bs[(wc * (BN / 2) + n * 16 + lr) * 32 + lk];
#pragma unroll
        for (int m = 0; m < 4; ++m)
#pragma unroll
            for (int n = 0; n < NFRAG; ++n)
                acc[m][n] = __builtin_amdgcn_mfma_f32_16x16x32_bf16(
                    af[m], bfr[n], acc[m][n], 0, 0, 0);
    }

    // epilogue: C/D mapping col = lane&15, row = (lane>>4)*4 + reg
    const int mBase = m0 + wr * 64, nBase = n0 + wc * (BN / 2);
#pragma unroll
    for (int m = 0; m < 4; ++m) {
#pragma unroll
        for (int n = 0; n < NFRAG; ++n) {
            const int col = nBase + n * 16 + lr;
            if (col < Nreal) {
#pragma unroll
                for (int j = 0; j < 4; ++j) {
                    const int row = mBase + m * 16 + (ln >> 4) * 4 + j;
                    float v = acc[m][n][j];
                    if (BIAS == 1) v += bias[col];
                    if (BIAS == 2) v += bias[row];
                    if (OUTBF) {
                        Ch[(size_t)row * ldc + col] = __float2bfloat16(v);
                        if (DUAL) C2[(size_t)row * ldc + col] = v;
                    } else {
                        Cf[(size_t)row * ldc + col] = v;
                    }
                }
            }
        }
    }
}

// ---------------------------------------------------------------------------
// Weight fp32 -> bf16 conversion (+ zero pad for in_proj rows 2192..2303)
// ---------------------------------------------------------------------------
#define SZ_PI  (512 * 512)
#define SZ_PO  (512 * 512)
#define SZ_OP  (512 * 1024)
#define SZ_IP  (DINPROJ * 512)
#define SZ_IPP (NPAD_IP * 512)
#define SZ_ALL (SZ_PI + SZ_PO + SZ_OP + SZ_IPP)

__global__ __launch_bounds__(256) void prep_weights(
    const float* __restrict__ pi, const float* __restrict__ po,
    const float* __restrict__ op, const float* __restrict__ ip,
    bf16* __restrict__ wpi, bf16* __restrict__ wpo,
    bf16* __restrict__ wop, bf16* __restrict__ wip)
{
    for (int idx = blockIdx.x * 256 + threadIdx.x; idx < SZ_ALL;
         idx += gridDim.x * 256) {
        if (idx < SZ_PI) {
            wpi[idx] = __float2bfloat16(pi[idx]);
        } else if (idx < SZ_PI + SZ_PO) {
            int j = idx - SZ_PI; wpo[j] = __float2bfloat16(po[j]);
        } else if (idx < SZ_PI + SZ_PO + SZ_OP) {
            int j = idx - SZ_PI - SZ_PO; wop[j] = __float2bfloat16(op[j]);
        } else {
            int j = idx - SZ_PI - SZ_PO - SZ_OP;
            wip[j] = (j < SZ_IP) ? __float2bfloat16(ip[j]) : __float2bfloat16(0.f);
        }
    }
}

// ---------------------------------------------------------------------------
// hs fp32 [512 c][4096 v] -> hsT bf16 [4096 v][512 c]
// ---------------------------------------------------------------------------
__global__ __launch_bounds__(256) void transpose_hs(
    const float* __restrict__ hs, bf16* __restrict__ hsT)
{
    __shared__ float tile[32][33];
    const int v0 = blockIdx.x * 32, c0 = blockIdx.y * 32;
    const int tx = threadIdx.x, ty = threadIdx.y;   // 32 x 8
#pragma unroll
    for (int i = 0; i < 4; ++i)
        tile[ty + 8 * i][tx] = hs[(size_t)(c0 + ty + 8 * i) * TOK + v0 + tx];
    __syncthreads();
#pragma unroll
    for (int i = 0; i < 4; ++i)
        hsT[(size_t)(v0 + ty + 8 * i) * DMODEL + c0 + tx] =
            __float2bfloat16(tile[tx][ty + 8 * i]);
}

// ---------------------------------------------------------------------------
// Recompute the 16 dt columns of zxbcdt in fp32 (exp-sensitive path).
// One block per token v; 4 waves x 4 heads each; lane covers 8 of 512 k.
// ---------------------------------------------------------------------------
__global__ __launch_bounds__(256) void dt_fix_kernel(
    const float* __restrict__ xv32, const float* __restrict__ in_proj_w,
    float* __restrict__ zxbcdt)
{
    const int v = blockIdx.x;
    const int w = threadIdx.x >> 6, l = threadIdx.x & 63;
    const float4* xr = (const float4*)(xv32 + (size_t)v * DMODEL);
    const float4 x0 = xr[l * 2], x1 = xr[l * 2 + 1];
#pragma unroll
    for (int hh = 0; hh < 4; ++hh) {
        const int h = w * 4 + hh;
        const float4* wr = (const float4*)(in_proj_w + (size_t)(DTOFF + h) * DMODEL);
        const float4 w0 = wr[l * 2], w1 = wr[l * 2 + 1];
        float dot = x0.x * w0.x + x0.y * w0.y + x0.z * w0.z + x0.w * w0.w
                  + x1.x * w1.x + x1.y * w1.y + x1.z * w1.z + x1.w * w1.w;
#pragma unroll
        for (int off = 32; off >= 1; off >>= 1) dot += __shfl_xor(dot, off);
        if (l == 0) zxbcdt[(size_t)v * DINPROJ + DTOFF + h] = dot;
    }
}

// ---------------------------------------------------------------------------
// Fused conv + SSD "scan" + D-skip + z-gating + RMSNorm.
// One block per sequence n: 1024 threads = 16 waves; wave = head h, lane = p.
// Thread tid also owns conv channel ch = tid of the x-part.
//
// SSD (exact for T=16):
//   y_t[p] = sum_{s<=t} exp(a*(cum_t - cum_s)) * (C_t . B_s) * dt_s * x_s[p]
// ---------------------------------------------------------------------------
__global__ __launch_bounds__(1024) void ssd_scan_kernel(
    const float* __restrict__ zxbcdt, const float* __restrict__ conv_w,
    const float* __restrict__ conv_b, const float* __restrict__ dt_bias,
    const float* __restrict__ A_log, const float* __restrict__ Dp,
    const float* __restrict__ norm_w, bf16* __restrict__ yn)
{
    const int n = blockIdx.x;
    const int tid = threadIdx.x;
    const int h = tid >> 6, p = tid & 63;

    __shared__ float Bsh[16][68];      // [t][s-state]
    __shared__ float Csh[16][68];
    __shared__ float Gsh[16][16];      // [t][s] = C_t . B_s
    __shared__ float dtv_sh[16][16];   // [h][t]
    __shared__ float cum_sh[16][16];   // [h][t] inclusive cumsum of dtv
    __shared__ float Msh[16][256];     // [h][t*16+s]
    __shared__ float red[16][17];      // [t][h]
    __shared__ float scale_sh[16];

    // ---- phase 0: conv(x-part) into registers; conv(B/C) into LDS ----
    float ld[16];
#pragma unroll
    for (int t = 0; t < 16; ++t)
        ld[t] = zxbcdt[(size_t)(t * 256 + n) * DINPROJ + DINNER + tid];

    const float cw0 = conv_w[tid * 4 + 0], cw1 = conv_w[tid * 4 + 1],
                cw2 = conv_w[tid * 4 + 2], cw3 = conv_w[tid * 4 + 3];
    const float cb = conv_b[tid];
    float xs[16];
#pragma unroll
    for (int t = 0; t < 16; ++t) {
        float a = fmaf(ld[t], cw3, cb);
        if (t >= 1) a = fmaf(ld[t - 1], cw2, a);
        if (t >= 2) a = fmaf(ld[t - 2], cw1, a);
        if (t >= 3) a = fmaf(ld[t - 3], cw0, a);
        xs[t] = a / (1.f + __expf(-a));
    }

    if (tid < 128) {   // waves 0,1: also conv the B/C channels (1024+tid)
        const int ch2 = 1024 + tid;
        const float dw0 = conv_w[ch2 * 4 + 0], dw1 = conv_w[ch2 * 4 + 1],
                    dw2 = conv_w[ch2 * 4 + 2], dw3 = conv_w[ch2 * 4 + 3];
        const float db = conv_b[ch2];
        float q0 = 0.f, q1 = 0.f, q2 = 0.f;   // inputs at t-3,t-2,t-1
#pragma unroll
        for (int t = 0; t < 16; ++t) {
            const float cur = zxbcdt[(size_t)(t * 256 + n) * DINPROJ + DINNER + ch2];
            float a = fmaf(cur, dw3, db);
            a = fmaf(q2, dw2, a);
            a = fmaf(q1, dw1, a);
            a = fmaf(q0, dw0, a);
            const float val = a / (1.f + __expf(-a));
            if (tid < 64) Bsh[t][tid] = val; else Csh[t][tid - 64] = val;
            q0 = q1; q1 = q2; q2 = cur;
        }
    }

    // ---- phase 1: per-head dt (softplus) + inclusive cumsum over t ----
    const float a_h = -__expf(A_log[h]);
    float dtv_l = 0.f;
    if (p < 16) {
        const float raw = zxbcdt[(size_t)(p * 256 + n) * DINPROJ + DTOFF + h]
                          + dt_bias[h];
        dtv_l = (raw > 20.f) ? raw : log1pf(__expf(raw));
    }
    float cum_l = dtv_l;
#pragma unroll
    for (int off = 1; off < 16; off <<= 1) {
        const float tmp = __shfl_up(cum_l, off);
        if (p >= off) cum_l += tmp;
    }
    if (p < 16) { dtv_sh[h][p] = dtv_l; cum_sh[h][p] = cum_l; }
    __syncthreads();

    // ---- phase 2: G[t][s] = C_t . B_s (head-independent) ----
    if (tid < 256) {
        const int t = tid >> 4, s = tid & 15;
        float acc = 0.f;
#pragma unroll
        for (int k = 0; k < 64; ++k)
            acc = fmaf(Csh[t][k], Bsh[s][k], acc);
        Gsh[t][s] = acc;
    }
    __syncthreads();

    // ---- phase 3: per-head mask M[t][s] = exp(a*(cum_t-cum_s))*G*dt_s ----
#pragma unroll
    for (int q = 0; q < 4; ++q) {
        const int idx = p * 4 + q;
        const int t = idx >> 4, s = idx & 15;
        float m = 0.f;
        if (s <= t)
            m = __expf(a_h * (cum_sh[h][t] - cum_sh[h][s]))
                * Gsh[t][s] * dtv_sh[h][s];
        Msh[h][idx] = m;
    }
    // Msh is wave-private (written & read by wave h only) -> no barrier needed.

    // issue z loads now; latency hides under phase 4 compute
    float zl[16];
#pragma unroll
    for (int t = 0; t < 16; ++t)
        zl[t] = zxbcdt[(size_t)(t * 256 + n) * DINPROJ + tid];

    // ---- phase 4: Y = M . x  + D*x, then gate with silu(z) ----
    const float Dh = Dp[h];
    const float nw = norm_w[tid];
    float g[16];
#pragma unroll
    for (int t = 0; t < 16; ++t) {
        float y = 0.f;
#pragma unroll
        for (int s = 0; s <= t; ++s)
            y = fmaf(Msh[h][t * 16 + s], xs[s], y);
        y = fmaf(Dh, xs[t], y);
        const float z = zl[t];
        g[t] = y * (z / (1.f + __expf(-z)));
    }

    // ---- phase 5: RMS norm over the 1024 channels of each token t ----
#pragma unroll
    for (int t = 0; t < 16; ++t) {
        float ss = g[t] * g[t];
#pragma unroll
        for (int off = 32; off >= 1; off >>= 1) ss += __shfl_xor(ss, off);
        if (p == 0) red[t][h] = ss;
    }
    __syncthreads();
    if (p < 16) {   // wave h reduces token t=h across heads
        float r = red[h][p];
#pragma unroll
        for (int off = 1; off < 16; off <<= 1) r += __shfl_xor(r, off);
        if (p == 0) scale_sh[h] = rsqrtf(r * (1.f / 1024.f) + 1e-5f);
    }
    __syncthreads();

    // ---- phase 6: write yn (bf16, v-order) ----
#pragma unroll
    for (int t = 0; t < 16; ++t)
        yn[(size_t)(t * 256 + n) * DINNER + tid] =
            __float2bfloat16(g[t] * scale_sh[t] * nw);
}

// ---------------------------------------------------------------------------
extern "C" void kernel_launch(void* const* d_in, const int* in_sizes, int n_in,
                              void* d_out, int out_size, void* d_ws, size_t ws_size,
                              hipStream_t stream) {
    const float* hs         = (const float*)d_in[0];   // (1,512,16,16,16)
    const float* proj_in_w  = (const float*)d_in[1];   // (512,512)
    const float* proj_in_b  = (const float*)d_in[2];   // (512)
    const float* proj_out_w = (const float*)d_in[3];   // (512,512)
    const float* proj_out_b = (const float*)d_in[4];   // (512)
    const float* in_proj_w  = (const float*)d_in[5];   // (2192,512)
    const float* conv_w     = (const float*)d_in[6];   // (1152,4)
    const float* conv_b     = (const float*)d_in[7];   // (1152)
    const float* dt_bias    = (const float*)d_in[8];   // (16)
    const float* A_log      = (const float*)d_in[9];   // (16)
    const float* Dp         = (const float*)d_in[10];  // (16)
    const float* norm_w     = (const float*)d_in[11];  // (1024)
    const float* out_proj_w = (const float*)d_in[12];  // (512,1024)
    float* out = (float*)d_out;

    // workspace layout (fp32 first, then bf16)
    float* ws      = (float*)d_ws;
    float* zxbcdt  = ws;                                   // 4096*2192 f32
    float* xv32    = zxbcdt + (size_t)TOK * DINPROJ;       // 4096*512  f32
    bf16*  bfb     = (bf16*)(xv32 + (size_t)TOK * DMODEL);
    bf16*  hsT     = bfb;                                  // 4096*512
    bf16*  xv_bf   = hsT + (size_t)TOK * DMODEL;           // 4096*512
    bf16*  yn      = xv_bf + (size_t)TOK * DMODEL;         // 4096*1024
    bf16*  y2      = yn + (size_t)TOK * DINNER;            // 4096*512
    bf16*  wpi     = y2 + (size_t)TOK * DMODEL;            // 512*512
    bf16*  wpo     = wpi + SZ_PI;                          // 512*512
    bf16*  wop     = wpo + SZ_PO;                          // 512*1024
    bf16*  wip     = wop + SZ_OP;                          // 2304*512

    // P0: weights -> bf16 (+pad), hs -> transposed bf16
    prep_weights<<<1024, 256, 0, stream>>>(proj_in_w, proj_out_w, out_proj_w,
                                           in_proj_w, wpi, wpo, wop, wip);
    transpose_hs<<<dim3(128, 16), dim3(32, 8), 0, stream>>>(hs, hsT);

    // K1: xv[v][d] = hsT[v][:] . wpi[d][:] + b[d]   (bf16 out + fp32 dual)
    mfma_gemm<2, true, true, 1><<<dim3(32, 8), 256, 0, stream>>>(
        hsT, wpi, proj_in_b, nullptr, xv_bf, xv32, DMODEL, DMODEL, DMODEL, DMODEL, DMODEL);

    // K2: zxbcdt[v][e] = xv[v][:] . wip[e][:]   (fp32 out, N guarded at 2192)
    mfma_gemm<4, false, false, 0><<<dim3(32, 18), 256, 0, stream>>>(
        xv_bf, wip, nullptr, zxbcdt, nullptr, nullptr, DINPROJ, DMODEL, DMODEL, DMODEL, DINPROJ);

    // K2b: recompute dt columns in fp32
    dt_fix_kernel<<<TOK, 256, 0, stream>>>(xv32, in_proj_w, zxbcdt);

    // K4: fused conv + SSD + gate + RMSNorm -> yn (bf16, v-order)
    ssd_scan_kernel<<<dim3(NSEQ), dim3(1024), 0, stream>>>(
        zxbcdt, conv_w, conv_b, dt_bias, A_log, Dp, norm_w, yn);

    // K6: y2[v][o] = yn[v][:] . wop[o][:]   (bf16 out)
    mfma_gemm<2, true, false, 0><<<dim3(32, 8), 256, 0, stream>>>(
        yn, wop, nullptr, nullptr, y2, nullptr, DMODEL, DINNER, DINNER, DINNER, DMODEL);

    // K7: out[c][v] = wpo[c][:] . y2[v][:] + pob[c]   (fp32, row-major = out layout)
    mfma_gemm<2, false, false, 2><<<dim3(4, 64), 256, 0, stream>>>(
        wpo, y2, proj_out_b, out, nullptr, nullptr, TOK, DMODEL, DMODEL, DMODEL, TOK);
}

// Round 4
// 118.476 us; speedup vs baseline: 3.4322x; 1.1165x over previous
//
#include <hip/hip_runtime.h>
#include <hip/hip_bf16.h>
#include <math.h>

// Problem constants
#define TT       16      // sequence length T
#define NSEQ     256     // B*H*W sequences
#define TOK      4096    // NSEQ * TT tokens
#define DMODEL   512
#define DINNER   1024
#define DSTATE   64
#define NHEADS   16
#define HEADDIM  64
#define CONVDIM  1152    // D_INNER + 2*D_STATE
#define DINPROJ  2192    // full in_proj rows
#define DTOFF    2176    // start of dt rows in in_proj
#define ZLD      2176    // zb row stride (z:0..1023, xBC:1024..2175)
#define NPAD_IP  2304    // in_proj rows padded to multiple of 128

using bf16x8 = __attribute__((ext_vector_type(8))) short;
using f32x4  = __attribute__((ext_vector_type(4))) float;
typedef __hip_bfloat16 bf16;

__device__ __forceinline__ void gload_lds16(const void* g, void* l) {
    __builtin_amdgcn_global_load_lds(
        (const __attribute__((address_space(1))) unsigned int*)g,
        (__attribute__((address_space(3))) unsigned int*)l,
        16, 0, 0);
}

// ---------------------------------------------------------------------------
// MFMA bf16 GEMM: C[M][N] = A[M][K] * B[N][K]^T (+ bias) (* rowscale[m])
// 128 x (NFRAG*32) tile, BK=32, 256 threads (4 waves, 2x2 wave grid).
// M % 128 == 0, K % 32 == 0, B has >= gridDim.y*BN valid rows (zero-padded),
// stores guarded by col < Nreal.
// BIAS: 0 none, 1 per-col (bias[n]), 2 per-row (bias[m]).
// OUTBF: store bf16 to Ch, else fp32 to Cf.  DUAL: also store fp32 to C2.
// SCALEROW: multiply output row m by rs[m] (fp32) before store.
// ---------------------------------------------------------------------------
template<int NFRAG, bool OUTBF, bool DUAL, int BIAS, bool SCALEROW>
__global__ __launch_bounds__(256) void mfma_gemm(
    const bf16* __restrict__ A, const bf16* __restrict__ B,
    const float* __restrict__ bias, const float* __restrict__ rs,
    float* __restrict__ Cf, bf16* __restrict__ Ch, float* __restrict__ C2,
    int Nreal, int K, int lda, int ldb, int ldc)
{
    constexpr int BN = NFRAG * 32;
    __shared__ short As[128 * 32];
    __shared__ short Bs[BN * 32];

    const int tid = threadIdx.x;
    const int wv = tid >> 6, ln = tid & 63;
    const int m0 = blockIdx.x * 128, n0 = blockIdx.y * BN;
    const int wr = wv >> 1, wc = wv & 1;        // 2x2 wave grid
    const int lr = ln & 15, lk = (ln >> 4) * 8; // fragment row / k-offset

    f32x4 acc[4][NFRAG];
#pragma unroll
    for (int m = 0; m < 4; ++m)
#pragma unroll
        for (int n = 0; n < NFRAG; ++n) acc[m][n] = (f32x4){0.f, 0.f, 0.f, 0.f};

    for (int k0 = 0; k0 < K; k0 += 32) {
        __syncthreads();   // previous iteration's reads done
#pragma unroll
        for (int r = 0; r < 2; ++r) {
            const int ofs = r * 4096 + tid * 16;    // byte in 8KB A tile
            const int row = ofs >> 6;               // 64 B per row
            const int ke  = (ofs & 63) >> 1;        // element in row
            gload_lds16(A + (size_t)(m0 + row) * lda + k0 + ke, (char*)As + ofs);
        }
#pragma unroll
        for (int r = 0; r < NFRAG / 2; ++r) {
            const int ofs = r * 4096 + tid * 16;
            const int row = ofs >> 6;
            const int ke  = (ofs & 63) >> 1;
            gload_lds16(B + (size_t)(n0 + row) * ldb + k0 + ke, (char*)Bs + ofs);
        }
        __syncthreads();   // staging complete

        bf16x8 af[4], bfr[NFRAG];
#pragma unroll
        for (int m = 0; m < 4; ++m)
            af[m] = *(const bf16x8*)&As[(wr * 64 + m * 16 + lr) * 32 + lk];
#pragma unroll
        for (int n = 0; n < NFRAG; ++n)
            bfr[n] = *(const bf16x8*)&Bs[(wc * (BN / 2) + n * 16 + lr) * 32 + lk];
#pragma unroll
        for (int m = 0; m < 4; ++m)
#pragma unroll
            for (int n = 0; n < NFRAG; ++n)
                acc[m][n] = __builtin_amdgcn_mfma_f32_16x16x32_bf16(
                    af[m], bfr[n], acc[m][n], 0, 0, 0);
    }

    // epilogue: C/D mapping col = lane&15, row = (lane>>4)*4 + reg
    const int mBase = m0 + wr * 64, nBase = n0 + wc * (BN / 2);
#pragma unroll
    for (int m = 0; m < 4; ++m) {
#pragma unroll
        for (int n = 0; n < NFRAG; ++n) {
            const int col = nBase + n * 16 + lr;
            if (col < Nreal) {
#pragma unroll
                for (int j = 0; j < 4; ++j) {
                    const int row = mBase + m * 16 + (ln >> 4) * 4 + j;
                    float v = acc[m][n][j];
                    if (BIAS == 1) v += bias[col];
                    if (BIAS == 2) v += bias[row];
                    if (SCALEROW) v *= rs[row];
                    if (OUTBF) {
                        Ch[(size_t)row * ldc + col] = __float2bfloat16(v);
                        if (DUAL) C2[(size_t)row * ldc + col] = v;
                    } else {
                        Cf[(size_t)row * ldc + col] = v;
                    }
                }
            }
        }
    }
}

// ---------------------------------------------------------------------------
// Weight fp32 -> bf16 conversion. wop gets norm_w folded in; in_proj padded.
// ---------------------------------------------------------------------------
#define SZ_PI  (512 * 512)
#define SZ_PO  (512 * 512)
#define SZ_OP  (512 * 1024)
#define SZ_IP  (DINPROJ * 512)
#define SZ_IPP (NPAD_IP * 512)
#define SZ_ALL (SZ_PI + SZ_PO + SZ_OP + SZ_IPP)

__global__ __launch_bounds__(256) void prep_weights(
    const float* __restrict__ pi, const float* __restrict__ po,
    const float* __restrict__ op, const float* __restrict__ ip,
    const float* __restrict__ nw,
    bf16* __restrict__ wpi, bf16* __restrict__ wpo,
    bf16* __restrict__ wop, bf16* __restrict__ wip)
{
    for (int idx = blockIdx.x * 256 + threadIdx.x; idx < SZ_ALL;
         idx += gridDim.x * 256) {
        if (idx < SZ_PI) {
            wpi[idx] = __float2bfloat16(pi[idx]);
        } else if (idx < SZ_PI + SZ_PO) {
            int j = idx - SZ_PI; wpo[j] = __float2bfloat16(po[j]);
        } else if (idx < SZ_PI + SZ_PO + SZ_OP) {
            int j = idx - SZ_PI - SZ_PO;
            wop[j] = __float2bfloat16(op[j] * nw[j & 1023]);  // fold RMS weight
        } else {
            int j = idx - SZ_PI - SZ_PO - SZ_OP;
            wip[j] = (j < SZ_IP) ? __float2bfloat16(ip[j]) : __float2bfloat16(0.f);
        }
    }
}

// ---------------------------------------------------------------------------
// hs fp32 [512 c][4096 v] -> hsT bf16 [4096 v][512 c]
// ---------------------------------------------------------------------------
__global__ __launch_bounds__(256) void transpose_hs(
    const float* __restrict__ hs, bf16* __restrict__ hsT)
{
    __shared__ float tile[32][33];
    const int v0 = blockIdx.x * 32, c0 = blockIdx.y * 32;
    const int tx = threadIdx.x, ty = threadIdx.y;   // 32 x 8
#pragma unroll
    for (int i = 0; i < 4; ++i)
        tile[ty + 8 * i][tx] = hs[(size_t)(c0 + ty + 8 * i) * TOK + v0 + tx];
    __syncthreads();
#pragma unroll
    for (int i = 0; i < 4; ++i)
        hsT[(size_t)(v0 + ty + 8 * i) * DMODEL + c0 + tx] =
            __float2bfloat16(tile[tx][ty + 8 * i]);
}

// ---------------------------------------------------------------------------
// dt in fp32 (exp-sensitive path): dtf[v][h] = xv32[v] . in_proj_w[DTOFF+h]
// ---------------------------------------------------------------------------
__global__ __launch_bounds__(256) void dt_fix_kernel(
    const float* __restrict__ xv32, const float* __restrict__ in_proj_w,
    float* __restrict__ dtf)
{
    const int v = blockIdx.x;
    const int w = threadIdx.x >> 6, l = threadIdx.x & 63;
    const float4* xr = (const float4*)(xv32 + (size_t)v * DMODEL);
    const float4 x0 = xr[l * 2], x1 = xr[l * 2 + 1];
#pragma unroll
    for (int hh = 0; hh < 4; ++hh) {
        const int h = w * 4 + hh;
        const float4* wr = (const float4*)(in_proj_w + (size_t)(DTOFF + h) * DMODEL);
        const float4 w0 = wr[l * 2], w1 = wr[l * 2 + 1];
        float dot = x0.x * w0.x + x0.y * w0.y + x0.z * w0.z + x0.w * w0.w
                  + x1.x * w1.x + x1.y * w1.y + x1.z * w1.z + x1.w * w1.w;
#pragma unroll
        for (int off = 32; off >= 1; off >>= 1) dot += __shfl_xor(dot, off);
        if (l == 0) dtf[(size_t)v * 16 + h] = dot;
    }
}

// ---------------------------------------------------------------------------
// Fused conv + SSD + D-skip + z-gating; emits unnormalized g (bf16) and
// per-(token, head-quad) partial sum-of-squares.
// Grid (n, hq): 256 x 4 blocks, 256 threads = 4 waves; wave w = head hq*4+w.
// Thread's x channel: ch = hq*256 + tid = h*64 + p.
//
// SSD (exact for T=16):
//   y_t[p] = sum_{s<=t} exp(a*(cum_t - cum_s)) * (C_t . B_s) * dt_s * x_s[p]
// ---------------------------------------------------------------------------
__global__ __launch_bounds__(256) void ssd_kernel(
    const bf16* __restrict__ zb, const float* __restrict__ dtf,
    const float* __restrict__ conv_w, const float* __restrict__ conv_b,
    const float* __restrict__ dt_bias, const float* __restrict__ A_log,
    const float* __restrict__ Dp,
    bf16* __restrict__ gb, float* __restrict__ part)
{
    const int n = blockIdx.x, hq = blockIdx.y;
    const int tid = threadIdx.x;
    const int w = tid >> 6, p = tid & 63;
    const int h = hq * 4 + w;
    const int ch = hq * 256 + tid;          // x / z / g channel

    __shared__ float Bsh[16][68];           // [t][state]
    __shared__ float Csh[16][68];
    __shared__ float Gsh[16][16];           // [t][s] = C_t . B_s
    __shared__ float Msh[4][256];           // per-wave mask [t*16+s]
    __shared__ float red4[16][4];           // [t][wave] partial sumsq

    // ---- phase 0: load x-part (bf16) for own channel, all 16 t ----
    float ld[16];
#pragma unroll
    for (int t = 0; t < 16; ++t)
        ld[t] = __bfloat162float(zb[(size_t)(t * 256 + n) * ZLD + 1024 + ch]);

    const float cw0 = conv_w[ch * 4 + 0], cw1 = conv_w[ch * 4 + 1],
                cw2 = conv_w[ch * 4 + 2], cw3 = conv_w[ch * 4 + 3];
    const float cb = conv_b[ch];
    float xs[16];
#pragma unroll
    for (int t = 0; t < 16; ++t) {
        float a = fmaf(ld[t], cw3, cb);
        if (t >= 1) a = fmaf(ld[t - 1], cw2, a);
        if (t >= 2) a = fmaf(ld[t - 2], cw1, a);
        if (t >= 3) a = fmaf(ld[t - 3], cw0, a);
        xs[t] = a / (1.f + __expf(-a));
    }

    // ---- conv B/C channels (cols 2048..2175) by threads 0..127 ----
    if (tid < 128) {
        const int cc = 1024 + tid;          // conv channel index
        const float dw0 = conv_w[cc * 4 + 0], dw1 = conv_w[cc * 4 + 1],
                    dw2 = conv_w[cc * 4 + 2], dw3 = conv_w[cc * 4 + 3];
        const float db = conv_b[cc];
        float q0 = 0.f, q1 = 0.f, q2 = 0.f;
#pragma unroll
        for (int t = 0; t < 16; ++t) {
            const float cur =
                __bfloat162float(zb[(size_t)(t * 256 + n) * ZLD + 2048 + tid]);
            float a = fmaf(cur, dw3, db);
            a = fmaf(q2, dw2, a);
            a = fmaf(q1, dw1, a);
            a = fmaf(q0, dw0, a);
            const float val = a / (1.f + __expf(-a));
            if (tid < 64) Bsh[t][tid] = val; else Csh[t][tid - 64] = val;
            q0 = q1; q1 = q2; q2 = cur;
        }
    }

    // ---- per-head dt (softplus, fp32) + inclusive cumsum over t ----
    const float a_h = -__expf(A_log[h]);
    float dtv_l = 0.f;
    if (p < 16) {
        const float raw = dtf[(size_t)(p * 256 + n) * 16 + h] + dt_bias[h];
        dtv_l = (raw > 20.f) ? raw : log1pf(__expf(raw));
    }
    float cum_l = dtv_l;
#pragma unroll
    for (int off = 1; off < 16; off <<= 1) {
        const float tmp = __shfl_up(cum_l, off);
        if (p >= off) cum_l += tmp;
    }
    __syncthreads();   // Bsh/Csh ready

    // ---- G[t][s] = C_t . B_s (head-independent) ----
    {
        const int t = tid >> 4, s = tid & 15;
        float acc = 0.f;
#pragma unroll
        for (int k = 0; k < 64; ++k)
            acc = fmaf(Csh[t][k], Bsh[s][k], acc);
        Gsh[t][s] = acc;
    }
    __syncthreads();

    // ---- per-head mask M[t][s] = exp(a*(cum_t-cum_s)) * G * dt_s ----
    // lanes p<16 hold dtv/cum for t=p; broadcast via shfl
    float dtv_all[16], cum_all[16];
#pragma unroll
    for (int t = 0; t < 16; ++t) {
        dtv_all[t] = __shfl(dtv_l, t);
        cum_all[t] = __shfl(cum_l, t);
    }
#pragma unroll
    for (int q = 0; q < 4; ++q) {
        const int idx = p * 4 + q;
        const int t = idx >> 4, s = idx & 15;
        float m = 0.f;
        if (s <= t)
            m = __expf(a_h * (cum_all[t] - cum_all[s])) * Gsh[t][s] * dtv_all[s];
        Msh[w][idx] = m;   // wave-private; no barrier needed
    }

    // issue z loads; latency hides under phase 4 compute
    float zl[16];
#pragma unroll
    for (int t = 0; t < 16; ++t)
        zl[t] = __bfloat162float(zb[(size_t)(t * 256 + n) * ZLD + ch]);

    // ---- Y = M . x + D*x, gate with silu(z) ----
    const float Dh = Dp[h];
    float g[16];
#pragma unroll
    for (int t = 0; t < 16; ++t) {
        float y = 0.f;
#pragma unroll
        for (int s = 0; s <= t; ++s)
            y = fmaf(Msh[w][t * 16 + s], xs[s], y);
        y = fmaf(Dh, xs[t], y);
        g[t] = y * (zl[t] / (1.f + __expf(-zl[t])));
    }

    // ---- partial sum of squares per (t, wave) + write g ----
#pragma unroll
    for (int t = 0; t < 16; ++t) {
        float ss = g[t] * g[t];
#pragma unroll
        for (int off = 32; off >= 1; off >>= 1) ss += __shfl_xor(ss, off);
        if (p == 0) red4[t][w] = ss;
        gb[(size_t)(t * 256 + n) * DINNER + ch] = __float2bfloat16(g[t]);
    }
    __syncthreads();
    if (tid < 16)
        part[(size_t)(tid * 256 + n) * 4 + hq] =
            red4[tid][0] + red4[tid][1] + red4[tid][2] + red4[tid][3];
}

// ---------------------------------------------------------------------------
// scale[v] = rsqrt(mean over 1024 of g^2 + 1e-5)
// ---------------------------------------------------------------------------
__global__ __launch_bounds__(256) void scale_kernel(
    const float* __restrict__ part, float* __restrict__ scalev)
{
    const int v = blockIdx.x * 256 + threadIdx.x;
    const float4 pv = *(const float4*)(part + (size_t)v * 4);
    const float s = pv.x + pv.y + pv.z + pv.w;
    scalev[v] = rsqrtf(s * (1.f / 1024.f) + 1e-5f);
}

// ---------------------------------------------------------------------------
extern "C" void kernel_launch(void* const* d_in, const int* in_sizes, int n_in,
                              void* d_out, int out_size, void* d_ws, size_t ws_size,
                              hipStream_t stream) {
    const float* hs         = (const float*)d_in[0];   // (1,512,16,16,16)
    const float* proj_in_w  = (const float*)d_in[1];   // (512,512)
    const float* proj_in_b  = (const float*)d_in[2];   // (512)
    const float* proj_out_w = (const float*)d_in[3];   // (512,512)
    const float* proj_out_b = (const float*)d_in[4];   // (512)
    const float* in_proj_w  = (const float*)d_in[5];   // (2192,512)
    const float* conv_w     = (const float*)d_in[6];   // (1152,4)
    const float* conv_b     = (const float*)d_in[7];   // (1152)
    const float* dt_bias    = (const float*)d_in[8];   // (16)
    const float* A_log      = (const float*)d_in[9];   // (16)
    const float* Dp         = (const float*)d_in[10];  // (16)
    const float* norm_w     = (const float*)d_in[11];  // (1024)
    const float* out_proj_w = (const float*)d_in[12];  // (512,1024)
    float* out = (float*)d_out;

    // workspace layout (fp32 first, then bf16)
    float* ws      = (float*)d_ws;
    float* xv32    = ws;                                   // 4096*512 f32
    float* dtf     = xv32 + (size_t)TOK * DMODEL;          // 4096*16  f32
    float* part    = dtf + (size_t)TOK * 16;               // 4096*4   f32
    float* scalev  = part + (size_t)TOK * 4;               // 4096     f32
    bf16*  hsT     = (bf16*)(scalev + TOK);                // 4096*512
    bf16*  xv_bf   = hsT + (size_t)TOK * DMODEL;           // 4096*512
    bf16*  zb      = xv_bf + (size_t)TOK * DMODEL;         // 4096*2176
    bf16*  gb      = zb + (size_t)TOK * ZLD;               // 4096*1024
    bf16*  y2      = gb + (size_t)TOK * DINNER;            // 4096*512
    bf16*  wpi     = y2 + (size_t)TOK * DMODEL;            // 512*512
    bf16*  wpo     = wpi + SZ_PI;                          // 512*512
    bf16*  wop     = wpo + SZ_PO;                          // 512*1024 (nw folded)
    bf16*  wip     = wop + SZ_OP;                          // 2304*512

    // P0: weights -> bf16 (+pad, +nw fold), hs -> transposed bf16
    prep_weights<<<1024, 256, 0, stream>>>(proj_in_w, proj_out_w, out_proj_w,
                                           in_proj_w, norm_w, wpi, wpo, wop, wip);
    transpose_hs<<<dim3(128, 16), dim3(32, 8), 0, stream>>>(hs, hsT);

    // K1: xv[v][d] = hsT[v][:] . wpi[d][:] + b[d]   (bf16 out + fp32 dual)
    mfma_gemm<2, true, true, 1, false><<<dim3(32, 8), 256, 0, stream>>>(
        hsT, wpi, proj_in_b, nullptr, nullptr, xv_bf, xv32,
        DMODEL, DMODEL, DMODEL, DMODEL, DMODEL);

    // K2: zb[v][e] = xv[v][:] . wip[e][:]   (bf16 out, cols 0..2175)
    mfma_gemm<4, true, false, 0, false><<<dim3(32, 18), 256, 0, stream>>>(
        xv_bf, wip, nullptr, nullptr, nullptr, zb, nullptr,
        ZLD, DMODEL, DMODEL, DMODEL, ZLD);

    // K2b: dt columns in fp32 -> dtf
    dt_fix_kernel<<<TOK, 256, 0, stream>>>(xv32, in_proj_w, dtf);

    // K4: fused conv + SSD + gate -> gb (bf16) + partial sumsq
    ssd_kernel<<<dim3(NSEQ, 4), 256, 0, stream>>>(
        zb, dtf, conv_w, conv_b, dt_bias, A_log, Dp, gb, part);

    // K5: per-token RMS scale
    scale_kernel<<<dim3(TOK / 256), 256, 0, stream>>>(part, scalev);

    // K6: y2[v][o] = scale[v] * (gb[v][:] . wop[o][:])   (bf16 out)
    mfma_gemm<2, true, false, 0, true><<<dim3(32, 8), 256, 0, stream>>>(
        gb, wop, nullptr, scalev, nullptr, y2, nullptr,
        DMODEL, DINNER, DINNER, DINNER, DMODEL);

    // K7: out[c][v] = wpo[c][:] . y2[v][:] + pob[c]   (fp32, row-major out)
    mfma_gemm<2, false, false, 2, false><<<dim3(4, 64), 256, 0, stream>>>(
        wpo, y2, proj_out_b, nullptr, out, nullptr, nullptr,
        TOK, DMODEL, DMODEL, DMODEL, TOK);
}